// Round 9
// baseline (249.719 us; speedup 1.0000x reference)
//
#include <hip/hip_runtime.h>
#include <stdint.h>
#include <limits.h>

// StackMachineCell — split design (round 9).
// r8 post-mortem: monolithic kernel is issue-bound at 1 wave/SIMD (~150
// dependent insts/step ~ 1387 cy/step). Only the (s,r) recurrence is serial.
// Phase 1: minimal serial kernel -> trajectory (s,r) u16 per (t,b) in d_ws.
//          Forced steps (~50%) skip LDS+argmax entirely. f64 + i32-key DPP
//          argmax (bit-identical decisions to r8, which PASSED).
// Phase 2: embarrassingly parallel logit materialization, all f32,
//          full occupancy, coalesced — near the 237MB write roofline.
// ws layout: Mm64[128][34] @0 | Ms64[128][64] @34816 | Mm32 @100352 |
//            Ms32 @117760 | Mb32 @150528 | traj u16[262144] @216064 (740 KB).

#define TT 512
#define BB 512
#define HH 128
#define NSs 64
#define NMm 34
#define NBb 128

typedef unsigned short u16;

// i32 max via DPP; old=key, bound_ctrl=false -> disabled source lanes keep key
template <int CTRL, int RMASK>
__device__ __forceinline__ int dppmax(int key) {
  const int t = __builtin_amdgcn_update_dpp(key, key, CTRL, RMASK, 0xf, false);
  return t > key ? t : key;
}

__device__ __forceinline__ int wave_max_i32(int k) {
  k = dppmax<0x111, 0xf>(k);  // row_shr:1
  k = dppmax<0x112, 0xf>(k);  // row_shr:2
  k = dppmax<0x114, 0xf>(k);  // row_shr:4
  k = dppmax<0x118, 0xf>(k);  // row_shr:8
  k = dppmax<0x142, 0xa>(k);  // row_bcast:15
  k = dppmax<0x143, 0xc>(k);  // row_bcast:31
  return __builtin_amdgcn_readlane(k, 63);
}

// ---- precompute M: f64 (phase-1 argmax) + f32 (phase-2 outputs)
__global__ void precompute_M(const float* __restrict__ embed,
                             const float* __restrict__ Wm, const float* __restrict__ bm,
                             const float* __restrict__ Wb, const float* __restrict__ bb,
                             const float* __restrict__ Ws, const float* __restrict__ bs,
                             double* __restrict__ Mm64, double* __restrict__ Ms64,
                             float* __restrict__ Mm32, float* __restrict__ Ms32,
                             float* __restrict__ Mb32) {
  __shared__ double e[HH];
  const int v = blockIdx.x;
  const int tid = threadIdx.x;  // 256
  if (tid < HH) e[tid] = (double)embed[v * HH + tid];
  __syncthreads();
  if (tid < NMm) {
    const int j = tid;
    double acc = 0.0;
    for (int h = 0; h < HH; ++h) acc += e[h] * (double)Wm[h * NMm + j];
    acc += (double)bm[j];
    Mm64[v * NMm + j] = acc;
    Mm32[v * NMm + j] = (float)acc;
  } else if (tid < NMm + NSs) {
    const int j = tid - NMm;
    double acc = 0.0;
    for (int h = 0; h < HH; ++h) acc += e[h] * (double)Ws[h * NSs + j];
    acc += (double)bs[j];
    Ms64[v * NSs + j] = acc;
    Ms32[v * NSs + j] = (float)acc;
  } else if (tid < NMm + NSs + NBb) {
    const int j = tid - NMm - NSs;
    double acc = 0.0;
    for (int h = 0; h < HH; ++h) acc += e[h] * (double)Wb[h * NBb + j];
    Mb32[v * NBb + j] = (float)(acc + (double)bb[j]);
  }
}

// ---- phase 1: trajectory only. 2 waves/block, 1 batch element per wave.
__global__ __launch_bounds__(128) void sm_phase1(
    const int* __restrict__ x, const int* __restrict__ tact,
    const int* __restrict__ tstate, const int* __restrict__ forc,
    const float* __restrict__ Wm, const float* __restrict__ Ws,
    const double* __restrict__ Mm, const double* __restrict__ Ms,
    u16* __restrict__ traj) {
  __shared__ float sWm[96 * NMm];   // 13056 B (argmax path, f32 exact)
  __shared__ float sWs[96 * NSs];   // 24576 B
  const int tid = threadIdx.x;
  for (int i = tid; i < 96 * NMm; i += 128) sWm[i] = Wm[128 * NMm + i];
  for (int i = tid; i < 96 * NSs; i += 128) sWs[i] = Ws[128 * NSs + i];
  __syncthreads();

  const int lane = tid & 63;
  const int lane34 = (lane < NMm) ? lane : 0;
  const int b = blockIdx.x * 2 + (tid >> 6);

  // int prefetch as vector loads (vmcnt) via opaque v_mov (r6/r8 lesson)
  int iv;
  asm("v_mov_b32 %0, %1" : "=v"(iv) : "r"(b));
  const int v0 = x[iv];
  int ta = __builtin_amdgcn_readfirstlane(tact[iv]);
  int ts = __builtin_amdgcn_readfirstlane(tstate[iv]);
  int f  = __builtin_amdgcn_readfirstlane(forc[iv]);
  asm("v_mov_b32 %0, %1" : "=v"(iv) : "r"(BB + b));
  int vn  = x[iv];
  int ta1 = tact[iv], ts1 = tstate[iv], f1 = forc[iv];

  double Mm_c = Mm[v0 * NMm + lane34];
  double Ms_c = Ms[v0 * NSs + lane];

  int stackv = 0;   // lane i holds stack[i]
  int ptr = 0, r = 0, s = 0;

  for (int t = 0; t < TT; ++t) {
    // prefetch M gather for t+1, ints for t+2 (off critical chain)
    const double Mm_n = Mm[vn * NMm + lane34];
    const double Ms_n = Ms[vn * NSs + lane];
    const int i2 = (t + 2 < TT ? t + 2 : TT - 1) * BB + b;
    asm("v_mov_b32 %0, %1" : "=v"(iv) : "r"(i2));
    const int x2 = x[iv];
    const int ta2 = tact[iv], ts2 = tstate[iv], f2 = forc[iv];

    // record carry-in (s,r) for this step — phase 2 consumes it
    if (lane == 0) traj[t * BB + b] = (u16)(s | (r << 8));

    int act, ns;
    if (f > 0) {         // forced: no logits needed at all
      act = ta;
      ns = ts;
    } else {
      const int sr = 64 + r;
      const double lm  = Mm_c + (double)sWm[s * NMm + lane34] + (double)sWm[sr * NMm + lane34];
      const double lsv = Ms_c + (double)sWs[s * NSs + lane]   + (double)sWs[sr * NSs + lane];
      // i32 keys (r6-verified): trunc(val*2^24)<<6 | (63-lane)
      const int ivm = (int)(lm * 16777216.0);
      const int ivs = (int)(lsv * 16777216.0);
      int km = (lane < NMm) ? (int)(((unsigned)ivm << 6) | (unsigned)(63 - lane))
                            : INT_MIN;
      int ks = (int)(((unsigned)ivs << 6) | (unsigned)(63 - lane));
      km = wave_max_i32(km);
      ks = wave_max_i32(ks);
      act = 63 - (km & 63);
      ns  = 63 - (ks & 63);
    }

    const bool ispush = act >= 2;
    int npn = ptr + (ispush ? 1 : 0) - (act == 1 ? 1 : 0);
    npn = npn < 0 ? 0 : (npn > 63 ? 63 : npn);
    if (ispush && lane == npn) stackv = act - 2;
    r = __builtin_amdgcn_readlane(stackv, npn);
    ptr = npn;
    s = ns;

    Mm_c = Mm_n; Ms_c = Ms_n;
    vn = x2;
    ta = __builtin_amdgcn_readfirstlane(ta1);
    ts = __builtin_amdgcn_readfirstlane(ts1);
    f  = __builtin_amdgcn_readfirstlane(f1);
    ta1 = ta2; ts1 = ts2; f1 = f2;
  }
}

// ---- phase 2: materialize all logits. One row (t,b) per wave-iteration.
__global__ __launch_bounds__(256) void sm_phase2(
    const int* __restrict__ x, const u16* __restrict__ traj,
    const float* __restrict__ Wm, const float* __restrict__ Wb,
    const float* __restrict__ Ws,
    const float* __restrict__ Mm32, const float* __restrict__ Ms32,
    const float* __restrict__ Mb32, float* __restrict__ out) {
  const int tid = threadIdx.x;
  const int lane = tid & 63;
  const int wid = blockIdx.x * 4 + (tid >> 6);   // 2048 blocks -> 8192 waves
  float* outLM = out;                                  // [T,B,34]
  float* outLB = out + (size_t)TT * BB * NMm;          // [T,B,128]
  float* outLS = out + (size_t)TT * BB * (NMm + NBb);  // [T,B,64]

  for (int row = wid; row < TT * BB; row += 8192) {
    const int xv = x[row];          // wave-uniform -> scalar load
    const int pr = traj[row];
    const int s = pr & 255;
    const int r = pr >> 8;
    const int rs = 128 + s, rr = 192 + r;
    if (lane < NMm)
      outLM[(size_t)row * NMm + lane] =
          Mm32[xv * NMm + lane] + Wm[rs * NMm + lane] + Wm[rr * NMm + lane];
    outLS[(size_t)row * NSs + lane] =
        Ms32[xv * NSs + lane] + Ws[rs * NSs + lane] + Ws[rr * NSs + lane];
    outLB[(size_t)row * NBb + lane] =
        Mb32[xv * NBb + lane] + Wb[rs * NBb + lane] + Wb[rr * NBb + lane];
    outLB[(size_t)row * NBb + 64 + lane] =
        Mb32[xv * NBb + 64 + lane] + Wb[rs * NBb + 64 + lane] +
        Wb[rr * NBb + 64 + lane];
  }
}

extern "C" void kernel_launch(void* const* d_in, const int* in_sizes, int n_in,
                              void* d_out, int out_size, void* d_ws, size_t ws_size,
                              hipStream_t stream) {
  const int* x     = (const int*)d_in[0];
  const int* tactp = (const int*)d_in[1];
  const int* tstp  = (const int*)d_in[2];
  const int* forcp = (const int*)d_in[3];
  const float* embed = (const float*)d_in[4];
  const float* Wm = (const float*)d_in[5];
  const float* bm = (const float*)d_in[6];
  const float* Wb = (const float*)d_in[7];
  const float* bb = (const float*)d_in[8];
  const float* Ws = (const float*)d_in[9];
  const float* bs = (const float*)d_in[10];

  char* w = (char*)d_ws;
  double* Mm64 = (double*)(w);            //  34816 B
  double* Ms64 = (double*)(w + 34816);    //  65536 B
  float*  Mm32 = (float*)(w + 100352);    //  17408 B
  float*  Ms32 = (float*)(w + 117760);    //  32768 B
  float*  Mb32 = (float*)(w + 150528);    //  65536 B
  u16*    traj = (u16*)(w + 216064);      // 524288 B -> total 740352 B

  precompute_M<<<128, 256, 0, stream>>>(embed, Wm, bm, Wb, bb, Ws, bs,
                                        Mm64, Ms64, Mm32, Ms32, Mb32);
  sm_phase1<<<256, 128, 0, stream>>>(x, tactp, tstp, forcp, Wm, Ws,
                                     Mm64, Ms64, traj);
  sm_phase2<<<2048, 256, 0, stream>>>(x, traj, Wm, Wb, Ws,
                                      Mm32, Ms32, Mb32, (float*)d_out);
}